// Round 13
// baseline (198.915 us; speedup 1.0000x reference)
//
#include <hip/hip_runtime.h>
#include <math.h>

// Problem dims (fixed by the reference)
constexpr int NB  = 16;    // batch
constexpr int NP  = 1024;  // prev points
constexpr int NS  = 4096;  // skip points
constexpr int CP  = 256;   // prev channels
constexpr int CS  = 128;   // skip channels
constexpr int CIN = 384;   // CP + CS
constexpr int CO  = 256;   // output channels

constexpr int NCHUNK = 16;          // prev-point chunks for topk parallelism
constexpr int CHPTS  = NP / NCHUNK; // 64

typedef unsigned int uint;
typedef unsigned short ushort_t;
typedef __attribute__((ext_vector_type(8))) short short8;
typedef __attribute__((ext_vector_type(8))) unsigned short us8;
typedef __attribute__((ext_vector_type(4))) float f32x4;

__device__ __forceinline__ ushort_t f2bf(float f) {
  uint u = __float_as_uint(f);
  uint r = (u + 0x7fffu + ((u >> 16) & 1u)) >> 16;   // RNE
  return (ushort_t)r;
}
__device__ __forceinline__ float bf2f(ushort_t u) {
  return __uint_as_float(((uint)u) << 16);
}

__device__ __forceinline__ void gload16(const void* g, void* l) {
  __builtin_amdgcn_global_load_lds(
      (const __attribute__((address_space(1))) uint*)g,
      (__attribute__((address_space(3))) uint*)l, 16, 0, 0);
}

// Packed-key top-3 step (set-level correctness; masked-dist err <= 2^-13 rel).
__device__ __forceinline__ void tkp(float pxv, float pyv, float pzv, int pi,
                                    float qx, float qy, float qz,
                                    float& k0, float& k1, float& k2,
                                    float& rsum) {
  float dx = pxv - qx, dy = pyv - qy, dz = pzv - qz;
  float sq = fmaf(dz, dz, fmaf(dy, dy, fmaf(dx, dx, 1e-16f)));
  rsum += __builtin_amdgcn_rsqf(sq);
  float k = __uint_as_float((__float_as_uint(sq) & 0xFFFFFC00u) | (uint)pi);
  k2 = __builtin_amdgcn_fmed3f(k1, k2, k);
  k1 = __builtin_amdgcn_fmed3f(k0, k1, k);
  k0 = fminf(k0, k);
}

// ---------------------------------------------------------------------------
// topk stage 1 (unchanged)
__global__ __launch_bounds__(256) void topk_chunk_kernel(
    const float* __restrict__ xyz_prev, const float* __restrict__ xyz_skip,
    float* __restrict__ pbuf) {
  __shared__ float px[CHPTS], py[CHPTS], pz[CHPTS];
  int q  = blockIdx.y;
  int b  = blockIdx.z;
  int tid = threadIdx.x;
  if (tid < CHPTS) {
    const float* xp = xyz_prev + ((size_t)b * NP + q * CHPTS + tid) * 3;
    px[tid] = xp[0]; py[tid] = xp[1]; pz[tid] = xp[2];
  }
  __syncthreads();
  int nA = blockIdx.x * 512 + tid;
  int nB = nA + 256;
  const float* xqA = xyz_skip + ((size_t)b * NS + nA) * 3;
  const float* xqB = xyz_skip + ((size_t)b * NS + nB) * 3;
  float qxA = xqA[0], qyA = xqA[1], qzA = xqA[2];
  float qxB = xqB[0], qyB = xqB[1], qzB = xqB[2];
  float kA0 = INFINITY, kA1 = INFINITY, kA2 = INFINITY;
  float kB0 = INFINITY, kB1 = INFINITY, kB2 = INFINITY;
  float rsA = 0.f, rsB = 0.f;
  int pbase = q * CHPTS;
  for (int p = 0; p < CHPTS; p += 4) {
    float4 X = *(const float4*)&px[p];
    float4 Y = *(const float4*)&py[p];
    float4 Z = *(const float4*)&pz[p];
    tkp(X.x, Y.x, Z.x, pbase + p + 0, qxA, qyA, qzA, kA0, kA1, kA2, rsA);
    tkp(X.x, Y.x, Z.x, pbase + p + 0, qxB, qyB, qzB, kB0, kB1, kB2, rsB);
    tkp(X.y, Y.y, Z.y, pbase + p + 1, qxA, qyA, qzA, kA0, kA1, kA2, rsA);
    tkp(X.y, Y.y, Z.y, pbase + p + 1, qxB, qyB, qzB, kB0, kB1, kB2, rsB);
    tkp(X.z, Y.z, Z.z, pbase + p + 2, qxA, qyA, qzA, kA0, kA1, kA2, rsA);
    tkp(X.z, Y.z, Z.z, pbase + p + 2, qxB, qyB, qzB, kB0, kB1, kB2, rsB);
    tkp(X.w, Y.w, Z.w, pbase + p + 3, qxA, qyA, qzA, kA0, kA1, kA2, rsA);
    tkp(X.w, Y.w, Z.w, pbase + p + 3, qxB, qyB, qzB, kB0, kB1, kB2, rsB);
  }
  size_t PA = ((size_t)(b * NCHUNK + q) * NS + nA) * 4;
  size_t PB = ((size_t)(b * NCHUNK + q) * NS + nB) * 4;
  *(float4*)(pbuf + PA) = make_float4(kA0, kA1, kA2, rsA);
  *(float4*)(pbuf + PB) = make_float4(kB0, kB1, kB2, rsB);
}

// topk stage 2 (unchanged)
__global__ __launch_bounds__(256) void topk_merge_kernel(
    const float* __restrict__ pbuf, float* __restrict__ w3,
    int* __restrict__ idx3) {
  int gid = blockIdx.x * 256 + threadIdx.x;  // = b*NS + n
  int b = gid >> 12;
  int n = gid & (NS - 1);
  float k0 = INFINITY, k1 = INFINITY, k2 = INFINITY;
  float rsum = 0.f;
  #pragma unroll 4
  for (int q = 0; q < NCHUNK; q++) {
    float4 v = *(const float4*)(pbuf + ((size_t)(b * NCHUNK + q) * NS + n) * 4);
    rsum += v.w;
    k2 = __builtin_amdgcn_fmed3f(k1, k2, v.x);
    k1 = __builtin_amdgcn_fmed3f(k0, k1, v.x);
    k0 = fminf(k0, v.x);
    k2 = __builtin_amdgcn_fmed3f(k1, k2, v.y);
    k1 = __builtin_amdgcn_fmed3f(k0, k1, v.y);
    k0 = fminf(k0, v.y);
    k2 = __builtin_amdgcn_fmed3f(k1, k2, v.z);
    k1 = __builtin_amdgcn_fmed3f(k0, k1, v.z);
    k0 = fminf(k0, v.z);
  }
  float inv = 1.0f / rsum;
  uint u0 = __float_as_uint(k0), u1 = __float_as_uint(k1), u2 = __float_as_uint(k2);
  float d0 = __uint_as_float(u0 & 0xFFFFFC00u);
  float d1 = __uint_as_float(u1 & 0xFFFFFC00u);
  float d2 = __uint_as_float(u2 & 0xFFFFFC00u);
  size_t base = (size_t)gid * 3;
  w3[base + 0] = __builtin_amdgcn_rsqf(d0) * inv;
  w3[base + 1] = __builtin_amdgcn_rsqf(d1) * inv;
  w3[base + 2] = __builtin_amdgcn_rsqf(d2) * inv;
  idx3[base + 0] = (int)(u0 & 1023u);
  idx3[base + 1] = (int)(u1 & 1023u);
  idx3[base + 2] = (int)(u2 & 1023u);
}

// ---------------------------------------------------------------------------
// W fp32 -> bf16; block 0 also zeros the BN stats accumulators (512 each).
__global__ __launch_bounds__(256) void wcast_kernel(
    const float* __restrict__ W1, const float* __restrict__ W2,
    ushort_t* __restrict__ W1b, ushort_t* __restrict__ W2b,
    float* __restrict__ st1, float* __restrict__ st2) {
  int tid = threadIdx.x;
  if (blockIdx.x == 0) {
    st1[tid] = 0.f; st1[tid + 256] = 0.f;
    st2[tid] = 0.f; st2[tid + 256] = 0.f;
  }
  int t = blockIdx.x * 256 + tid;
  int n1 = CO * CIN / 4;
  if (t < n1) {
    float4 v = *(const float4*)(W1 + t * 4);
    ushort4 o; o.x = f2bf(v.x); o.y = f2bf(v.y); o.z = f2bf(v.z); o.w = f2bf(v.w);
    *(ushort4*)(W1b + t * 4) = o;
  } else {
    int u = t - n1;
    float4 v = *(const float4*)(W2 + u * 4);
    ushort4 o; o.x = f2bf(v.x); o.y = f2bf(v.y); o.z = f2bf(v.z); o.w = f2bf(v.w);
    *(ushort4*)(W2b + u * 4) = o;
  }
}

// ---------------------------------------------------------------------------
// Transpose points_prev [b][256][1024] f32 -> pptT [b][1024][256] bf16.
__global__ __launch_bounds__(256) void ppT_kernel(
    const float* __restrict__ pp, ushort_t* __restrict__ pptT) {
  __shared__ float tl[64][65];
  int p0 = blockIdx.x * 64, c0 = blockIdx.y * 64, b = blockIdx.z;
  int tid = threadIdx.x;
  const float* P = pp + (size_t)b * CP * NP;
  int pi4 = (tid & 15) * 4, ci = tid >> 4;
  #pragma unroll
  for (int r = 0; r < 4; r++) {
    int cc = ci + 16 * r;
    float4 v = *(const float4*)(P + (size_t)(c0 + cc) * NP + p0 + pi4);
    tl[cc][pi4] = v.x; tl[cc][pi4 + 1] = v.y; tl[cc][pi4 + 2] = v.z; tl[cc][pi4 + 3] = v.w;
  }
  __syncthreads();
  ushort_t* O = pptT + (size_t)b * NP * CP;
  int ci4 = (tid & 15) * 4, pi = tid >> 4;
  #pragma unroll
  for (int r = 0; r < 4; r++) {
    int pr = pi + 16 * r;
    ushort4 o;
    o.x = f2bf(tl[ci4 + 0][pr]); o.y = f2bf(tl[ci4 + 1][pr]);
    o.z = f2bf(tl[ci4 + 2][pr]); o.w = f2bf(tl[ci4 + 3][pr]);
    *(ushort4*)(O + (size_t)(p0 + pr) * CP + c0 + ci4) = o;
  }
}

// Transpose points_skip [b][128][4096] f32 -> x1[b][n][256..383] bf16.
__global__ __launch_bounds__(256) void skipT_kernel(
    const float* __restrict__ sk, ushort_t* __restrict__ x1) {
  __shared__ float tl[64][65];
  int n0 = blockIdx.x * 64, c0 = blockIdx.y * 64, b = blockIdx.z;
  int tid = threadIdx.x;
  const float* S = sk + (size_t)b * CS * NS;
  int ni4 = (tid & 15) * 4, ci = tid >> 4;
  #pragma unroll
  for (int r = 0; r < 4; r++) {
    int cc = ci + 16 * r;
    float4 v = *(const float4*)(S + (size_t)(c0 + cc) * NS + n0 + ni4);
    tl[cc][ni4] = v.x; tl[cc][ni4 + 1] = v.y; tl[cc][ni4 + 2] = v.z; tl[cc][ni4 + 3] = v.w;
  }
  __syncthreads();
  ushort_t* O = x1 + (size_t)b * NS * CIN;
  int ci4 = (tid & 15) * 4, ni = tid >> 4;
  #pragma unroll
  for (int r = 0; r < 4; r++) {
    int nr = ni + 16 * r;
    ushort4 o;
    o.x = f2bf(tl[ci4 + 0][nr]); o.y = f2bf(tl[ci4 + 1][nr]);
    o.z = f2bf(tl[ci4 + 2][nr]); o.w = f2bf(tl[ci4 + 3][nr]);
    *(ushort4*)(O + (size_t)(n0 + nr) * CIN + CP + c0 + ci4) = o;
  }
}

// Interp: x1[b][n][0..255] = sum_k w3[k] * pptT[idx[k]][c].
__global__ __launch_bounds__(256) void interp_kernel(
    const ushort_t* __restrict__ pptT, const float* __restrict__ w3,
    const int* __restrict__ idx3, ushort_t* __restrict__ x1) {
  int tid = threadIdx.x;
  int nl = tid >> 6, l = tid & 63;
  int b = blockIdx.y;
  int n = blockIdx.x * 4 + nl;
  size_t nb = (size_t)b * NS + n;
  int j0 = idx3[nb * 3 + 0], j1 = idx3[nb * 3 + 1], j2 = idx3[nb * 3 + 2];
  float w0 = w3[nb * 3 + 0], w1 = w3[nb * 3 + 1], w2 = w3[nb * 3 + 2];
  const ushort_t* P = pptT + (size_t)b * NP * CP;
  int c = l * 4;
  ushort4 g0 = *(const ushort4*)(P + (size_t)j0 * CP + c);
  ushort4 g1 = *(const ushort4*)(P + (size_t)j1 * CP + c);
  ushort4 g2 = *(const ushort4*)(P + (size_t)j2 * CP + c);
  ushort4 o;
  o.x = f2bf(w0 * bf2f(g0.x) + w1 * bf2f(g1.x) + w2 * bf2f(g2.x));
  o.y = f2bf(w0 * bf2f(g0.y) + w1 * bf2f(g1.y) + w2 * bf2f(g2.y));
  o.z = f2bf(w0 * bf2f(g0.z) + w1 * bf2f(g1.z) + w2 * bf2f(g2.z));
  o.w = f2bf(w0 * bf2f(g0.w) + w1 * bf2f(g1.w) + w2 * bf2f(g2.w));
  *(ushort4*)(x1 + nb * CIN + c) = o;
}

// ---------------------------------------------------------------------------
// Stats reducer: pstat [2048 blocks][512] -> stats[512]. grid 64 x 512.
__global__ __launch_bounds__(512) void statreduce_kernel(
    const float* __restrict__ pstat, float* __restrict__ stats) {
  int t = threadIdx.x;
  int r0 = blockIdx.x * 32;
  float a = 0.f;
  #pragma unroll
  for (int i = 0; i < 32; i++) a += pstat[(size_t)(r0 + i) * 512 + t];
  atomicAdd(&stats[t], a);
}

// ---------------------------------------------------------------------------
// TLP-first MFMA GEMM: 32x256 tile (full CO), grid 2048 (8 blocks/CU), BK=32,
// simple 2-barrier loop. 64B LDS rows, swizzle chunk^=(row>>1)&3 both sides
// (2-way = free). MODE 0: X = x1, gload_lds. MODE 1: X = relu(a1*y1+s1),
// reg-staged by threads<128. Output bf16 + per-block stat partials.
template <int MODE>
__global__ __launch_bounds__(256) void gemm_tlp_kernel(
    const ushort_t* __restrict__ X, const ushort_t* __restrict__ Wb,
    ushort_t* __restrict__ Yb, float* __restrict__ pstat,
    const float* __restrict__ stats_in, const float* __restrict__ g_in,
    const float* __restrict__ bt_in) {
  constexpr int KD = MODE ? CO : CIN;
  constexpr int NT = KD / 32;            // 12 or 8
  __shared__ __align__(16) char lds_raw[18432];  // X[32][32] 2K | W[256][32] 16K
  ushort_t* ldsX = (ushort_t*)lds_raw;
  ushort_t* ldsW = (ushort_t*)(lds_raw + 2048);
  __shared__ float ssum[CO], ssq[CO];
  __shared__ float a1s[MODE ? CO : 1], s1s[MODE ? CO : 1];

  int tid = threadIdx.x;
  int w = tid >> 6, l = tid & 63;
  int bid = blockIdx.x;
  int bz = bid >> 7, nt = bid & 127;
  int n0 = nt * 32;
  if (tid < 256) { ssum[tid] = 0.f; ssq[tid] = 0.f; }
  if constexpr (MODE == 1) {
    float cnt = (float)NB * (float)NS;
    float m = stats_in[tid] / cnt;
    float var = stats_in[CO + tid] / cnt - m * m;
    var = fmaxf(var, 0.f);
    float invs = rsqrtf(var + 1e-5f);
    float av = g_in[tid] * invs;
    a1s[tid] = av; s1s[tid] = bt_in[tid] - m * av;
  }
  __syncthreads();

  const ushort_t* Xb = X + (size_t)bz * NS * KD;
  // gload lane geometry: 4 lanes/row, chunk = l&3, row-in-group = l>>2
  int grow = l >> 2, gph = l & 3;
  // MODE1 reg-stage geometry (threads < 128): row = tid>>2, phys = tid&3
  int arow = tid >> 2, aph = tid & 3;
  int alg = aph ^ ((arow >> 1) & 3);

  f32x4 acc[2][4];
  #pragma unroll
  for (int i = 0; i < 2; i++)
    #pragma unroll
    for (int j = 0; j < 4; j++) acc[i][j] = {0.f, 0.f, 0.f, 0.f};

  int wo = w * 64;                       // per-wave o-span
  int lr = l & 15, lk = l >> 4;

  for (int t = 0; t < NT; t++) {
    int k0 = t * 32;
    // ---- stage W: each wave covers rows w*64 .. w*64+63 (4 issues)
    #pragma unroll
    for (int i = 0; i < 4; i++) {
      int rl = w * 64 + i * 16 + grow;
      int lg = gph ^ ((rl >> 1) & 3);
      gload16(Wb + (size_t)rl * KD + k0 + lg * 8,
              &ldsW[(w * 64 + i * 16) * 32]);
    }
    // ---- stage X
    if constexpr (MODE == 0) {
      if (w < 2) {
        int rl = w * 16 + grow;
        int lg = gph ^ ((rl >> 1) & 3);
        gload16(Xb + (size_t)(n0 + rl) * KD + k0 + lg * 8,
                &ldsX[(w * 16) * 32]);
      }
    } else {
      if (tid < 128) {
        us8 v = *(const us8*)(Xb + (size_t)(n0 + arow) * KD + k0 + alg * 8);
        const float* ap = &a1s[k0 + alg * 8];
        const float* sp = &s1s[k0 + alg * 8];
        us8 o;
        #pragma unroll
        for (int e = 0; e < 8; e++)
          o[e] = f2bf(fmaxf(fmaf(ap[e], bf2f(v[e]), sp[e]), 0.f));
        *(us8*)&ldsX[arow * 32 + aph * 8] = o;
      }
    }
    __syncthreads();
    // ---- compute: 2x4 frags, 8 MFMA per wave
    {
      short8 af[2], bfr[4];
      #pragma unroll
      for (int i = 0; i < 2; i++) {
        int rr = i * 16 + lr;
        int pc = lk ^ ((rr >> 1) & 3);
        af[i] = *(const short8*)&ldsX[rr * 32 + pc * 8];
      }
      #pragma unroll
      for (int j = 0; j < 4; j++) {
        int rw = wo + j * 16 + lr;
        int pc = lk ^ ((rw >> 1) & 3);
        bfr[j] = *(const short8*)&ldsW[rw * 32 + pc * 8];
      }
      __builtin_amdgcn_s_setprio(1);
      #pragma unroll
      for (int i = 0; i < 2; i++)
        #pragma unroll
        for (int j = 0; j < 4; j++)
          acc[i][j] = __builtin_amdgcn_mfma_f32_16x16x32_bf16(af[i], bfr[j], acc[i][j], 0, 0, 0);
      __builtin_amdgcn_s_setprio(0);
    }
    __syncthreads();
  }

  // ---- BN stat partials via LDS atomics (4 waves, disjoint o per wave -> 
  //      only cross-i contention), then coalesced C write via LDS.
  #pragma unroll
  for (int j = 0; j < 4; j++) {
    int ol = wo + j * 16 + lr;
    float ps = 0.f, pq = 0.f;
    #pragma unroll
    for (int i = 0; i < 2; i++)
      #pragma unroll
      for (int rg = 0; rg < 4; rg++) { float v = acc[i][j][rg]; ps += v; pq += v * v; }
    atomicAdd(&ssum[ol], ps);
    atomicAdd(&ssq[ol], pq);
  }
  ushort_t* lout = (ushort_t*)lds_raw;   // [32][264]
  #pragma unroll
  for (int i = 0; i < 2; i++)
    #pragma unroll
    for (int j = 0; j < 4; j++)
      #pragma unroll
      for (int rg = 0; rg < 4; rg++) {
        int nl = i * 16 + lk * 4 + rg;
        int ol = wo + j * 16 + lr;
        lout[nl * 264 + ol] = f2bf(acc[i][j][rg]);
      }
  __syncthreads();
  {
    int row = tid >> 3, co = (tid & 7) * 32;
    const ushort_t* src = lout + row * 264 + co;
    ushort_t* dst = Yb + ((size_t)bz * NS + n0 + row) * CO + co;
    #pragma unroll
    for (int k = 0; k < 4; k++)
      *(us8*)(dst + k * 8) = *(const us8*)(src + k * 8);
  }
  {
    float* ps = pstat + (size_t)bid * 512;
    ps[tid] = ssum[tid];
    ps[256 + tid] = ssq[tid];
  }
}

// Final BN2+ReLU with transpose, bf16 in [b][n][o] -> f32 out [b][o][n].
__global__ __launch_bounds__(256) void bnrelu_tr_kernel(
    const ushort_t* __restrict__ y2b, const float* __restrict__ stats_in,
    const float* __restrict__ g_in, const float* __restrict__ bt_in,
    float* __restrict__ out) {
  __shared__ float tl[64][65];
  __shared__ float a2s[64], s2s[64];
  int n0 = blockIdx.x * 64, o0 = blockIdx.y * 64, b = blockIdx.z;
  const ushort_t* Y = y2b + (size_t)b * NS * CO;
  int tid = threadIdx.x;
  if (tid < 64) {
    int o = o0 + tid;
    float cnt = (float)NB * (float)NS;
    float m = stats_in[o] / cnt;
    float var = stats_in[CO + o] / cnt - m * m;
    var = fmaxf(var, 0.f);
    float invs = rsqrtf(var + 1e-5f);
    float av = g_in[o] * invs;
    a2s[tid] = av; s2s[tid] = bt_in[o] - m * av;
  }
  int o8 = (tid & 7) * 8, row = tid >> 3;
  #pragma unroll
  for (int r = 0; r < 2; r++) {
    int ii = row + 32 * r;
    const ushort_t* src = Y + (size_t)(n0 + ii) * CO + o0 + o8;
    ushort4 v0 = *(const ushort4*)(src);
    ushort4 v1 = *(const ushort4*)(src + 4);
    tl[ii][o8 + 0] = bf2f(v0.x); tl[ii][o8 + 1] = bf2f(v0.y);
    tl[ii][o8 + 2] = bf2f(v0.z); tl[ii][o8 + 3] = bf2f(v0.w);
    tl[ii][o8 + 4] = bf2f(v1.x); tl[ii][o8 + 5] = bf2f(v1.y);
    tl[ii][o8 + 6] = bf2f(v1.z); tl[ii][o8 + 7] = bf2f(v1.w);
  }
  __syncthreads();
  float* O = out + (size_t)b * CO * NS;
  int ii4 = (tid & 15) * 4, j = tid >> 4;
  #pragma unroll
  for (int r = 0; r < 4; r++) {
    int jj = j + 16 * r;
    float av = a2s[jj], sv = s2s[jj];
    float4 v;
    v.x = fmaxf(fmaf(av, tl[ii4 + 0][jj], sv), 0.f);
    v.y = fmaxf(fmaf(av, tl[ii4 + 1][jj], sv), 0.f);
    v.z = fmaxf(fmaf(av, tl[ii4 + 2][jj], sv), 0.f);
    v.w = fmaxf(fmaf(av, tl[ii4 + 3][jj], sv), 0.f);
    *(float4*)(O + (size_t)(o0 + jj) * NS + n0 + ii4) = v;
  }
}

extern "C" void kernel_launch(void* const* d_in, const int* in_sizes, int n_in,
                              void* d_out, int out_size, void* d_ws, size_t ws_size,
                              hipStream_t stream) {
  const float* xyz_prev    = (const float*)d_in[0];
  const float* xyz_skip    = (const float*)d_in[1];
  const float* points_prev = (const float*)d_in[2];
  const float* points_skip = (const float*)d_in[3];
  const float* W1 = (const float*)d_in[4];
  const float* g1 = (const float*)d_in[5];
  const float* b1 = (const float*)d_in[6];
  const float* W2 = (const float*)d_in[7];
  const float* g2 = (const float*)d_in[8];
  const float* b2 = (const float*)d_in[9];
  float* out = (float*)d_out;

  // workspace layout (256B-aligned sequential allocs)
  char* W = (char*)d_ws;
  size_t off = 0;
  auto alloc = [&](size_t bytes) {
    size_t o = off; off = (off + bytes + 255) & ~(size_t)255; return o;
  };
  ushort_t* x1   = (ushort_t*)(W + alloc((size_t)NB * NS * CIN * 2));  // 50.3MB
  ushort_t* y1b  = (ushort_t*)(W + alloc((size_t)NB * NS * CO * 2));   // 33.6MB
  ushort_t* pptT = (ushort_t*)(W + alloc((size_t)NB * NP * CP * 2));   // 8.4MB
  ushort_t* W1b  = (ushort_t*)(W + alloc((size_t)CO * CIN * 2));
  ushort_t* W2b  = (ushort_t*)(W + alloc((size_t)CO * CO * 2));
  float* w3   = (float*)(W + alloc((size_t)NB * NS * 3 * 4));
  int*   idx3 = (int*)(W + alloc((size_t)NB * NS * 3 * 4));
  float* st1  = (float*)(W + alloc(512 * 4));
  float* st2  = (float*)(W + alloc(512 * 4));
  float* pst1 = (float*)(W + alloc(2048 * 512 * 4));                   // 4MB
  float* pst2 = (float*)(W + alloc(2048 * 512 * 4));                   // 4MB
  size_t y2_off = alloc((size_t)NB * NS * CO * 2);                     // 33.6MB bf16
  bool full = (ws_size >= off);
  ushort_t* y2b = full ? (ushort_t*)(W + y2_off) : (ushort_t*)d_out;
  // pbuf (16.8MB, transient, consumed before any y2 write) aliases y2 region
  float* pbuf = full ? (float*)(W + y2_off) : (float*)d_out;

  hipLaunchKernelGGL(topk_chunk_kernel, dim3(NS / 512, NCHUNK, NB), dim3(256), 0,
                     stream, xyz_prev, xyz_skip, pbuf);
  hipLaunchKernelGGL(topk_merge_kernel, dim3(NB * NS / 256), dim3(256), 0, stream,
                     pbuf, w3, idx3);
  hipLaunchKernelGGL(wcast_kernel, dim3((CO * CIN / 4 + CO * CO / 4 + 255) / 256),
                     dim3(256), 0, stream, W1, W2, W1b, W2b, st1, st2);
  hipLaunchKernelGGL(ppT_kernel, dim3(NP / 64, CP / 64, NB), dim3(256), 0, stream,
                     points_prev, pptT);
  hipLaunchKernelGGL(skipT_kernel, dim3(NS / 64, CS / 64, NB), dim3(256), 0, stream,
                     points_skip, x1);
  hipLaunchKernelGGL(interp_kernel, dim3(NS / 4, NB), dim3(256), 0, stream,
                     pptT, w3, idx3, x1);
  hipLaunchKernelGGL((gemm_tlp_kernel<0>), dim3(2048), dim3(256), 0, stream,
                     x1, W1b, y1b, pst1, (const float*)nullptr,
                     (const float*)nullptr, (const float*)nullptr);
  hipLaunchKernelGGL(statreduce_kernel, dim3(64), dim3(512), 0, stream, pst1, st1);
  hipLaunchKernelGGL((gemm_tlp_kernel<1>), dim3(2048), dim3(256), 0, stream,
                     y1b, W2b, y2b, pst2, st1, g1, b1);
  hipLaunchKernelGGL(statreduce_kernel, dim3(64), dim3(512), 0, stream, pst2, st2);
  if (full) {
    hipLaunchKernelGGL(bnrelu_tr_kernel, dim3(NS / 64, CO / 64, NB), dim3(256), 0,
                       stream, y2b, st2, g2, b2, out);
  } else {
    float* stage = (float*)d_ws;
    hipLaunchKernelGGL(bnrelu_tr_kernel, dim3(NS / 64, CO / 64, NB), dim3(256), 0,
                       stream, y2b, st2, g2, b2, stage);
    hipMemcpyAsync(out, stage, (size_t)NB * NS * CO * 4, hipMemcpyDeviceToDevice,
                   stream);
  }
}

// Round 14
// 166.541 us; speedup vs baseline: 1.1944x; 1.1944x over previous
//
#include <hip/hip_runtime.h>
#include <math.h>

// Problem dims (fixed by the reference)
constexpr int NB  = 16;    // batch
constexpr int NP  = 1024;  // prev points
constexpr int NS  = 4096;  // skip points
constexpr int CP  = 256;   // prev channels
constexpr int CS  = 128;   // skip channels
constexpr int CIN = 384;   // CP + CS
constexpr int CO  = 256;   // output channels

constexpr int NCHUNK = 16;          // prev-point chunks for topk parallelism
constexpr int CHPTS  = NP / NCHUNK; // 64
constexpr int NREP   = 8;           // BN-stat atomic replicas

typedef unsigned int uint;
typedef unsigned short ushort_t;
typedef __attribute__((ext_vector_type(8))) short short8;
typedef __attribute__((ext_vector_type(8))) unsigned short us8;
typedef __attribute__((ext_vector_type(4))) float f32x4;

__device__ __forceinline__ ushort_t f2bf(float f) {
  uint u = __float_as_uint(f);
  uint r = (u + 0x7fffu + ((u >> 16) & 1u)) >> 16;   // RNE
  return (ushort_t)r;
}
__device__ __forceinline__ float bf2f(ushort_t u) {
  return __uint_as_float(((uint)u) << 16);
}
__device__ __forceinline__ uint pk2(ushort_t lo, ushort_t hi) {
  return (uint)lo | ((uint)hi << 16);
}

__device__ __forceinline__ void gload16(const void* g, void* l) {
  __builtin_amdgcn_global_load_lds(
      (const __attribute__((address_space(1))) uint*)g,
      (__attribute__((address_space(3))) uint*)l, 16, 0, 0);
}

// Packed-key top-3 step (set-level correctness; masked-dist err <= 2^-13 rel).
__device__ __forceinline__ void tkp(float pxv, float pyv, float pzv, int pi,
                                    float qx, float qy, float qz,
                                    float& k0, float& k1, float& k2,
                                    float& rsum) {
  float dx = pxv - qx, dy = pyv - qy, dz = pzv - qz;
  float sq = fmaf(dz, dz, fmaf(dy, dy, fmaf(dx, dx, 1e-16f)));
  rsum += __builtin_amdgcn_rsqf(sq);
  float k = __uint_as_float((__float_as_uint(sq) & 0xFFFFFC00u) | (uint)pi);
  k2 = __builtin_amdgcn_fmed3f(k1, k2, k);
  k1 = __builtin_amdgcn_fmed3f(k0, k1, k);
  k0 = fminf(k0, k);
}

// ---------------------------------------------------------------------------
// topk stage 1 (unchanged from best config)
__global__ __launch_bounds__(256) void topk_chunk_kernel(
    const float* __restrict__ xyz_prev, const float* __restrict__ xyz_skip,
    float* __restrict__ pbuf) {
  __shared__ float px[CHPTS], py[CHPTS], pz[CHPTS];
  int q  = blockIdx.y;
  int b  = blockIdx.z;
  int tid = threadIdx.x;
  if (tid < CHPTS) {
    const float* xp = xyz_prev + ((size_t)b * NP + q * CHPTS + tid) * 3;
    px[tid] = xp[0]; py[tid] = xp[1]; pz[tid] = xp[2];
  }
  __syncthreads();
  int nA = blockIdx.x * 512 + tid;
  int nB = nA + 256;
  const float* xqA = xyz_skip + ((size_t)b * NS + nA) * 3;
  const float* xqB = xyz_skip + ((size_t)b * NS + nB) * 3;
  float qxA = xqA[0], qyA = xqA[1], qzA = xqA[2];
  float qxB = xqB[0], qyB = xqB[1], qzB = xqB[2];
  float kA0 = INFINITY, kA1 = INFINITY, kA2 = INFINITY;
  float kB0 = INFINITY, kB1 = INFINITY, kB2 = INFINITY;
  float rsA = 0.f, rsB = 0.f;
  int pbase = q * CHPTS;
  for (int p = 0; p < CHPTS; p += 4) {
    float4 X = *(const float4*)&px[p];
    float4 Y = *(const float4*)&py[p];
    float4 Z = *(const float4*)&pz[p];
    tkp(X.x, Y.x, Z.x, pbase + p + 0, qxA, qyA, qzA, kA0, kA1, kA2, rsA);
    tkp(X.x, Y.x, Z.x, pbase + p + 0, qxB, qyB, qzB, kB0, kB1, kB2, rsB);
    tkp(X.y, Y.y, Z.y, pbase + p + 1, qxA, qyA, qzA, kA0, kA1, kA2, rsA);
    tkp(X.y, Y.y, Z.y, pbase + p + 1, qxB, qyB, qzB, kB0, kB1, kB2, rsB);
    tkp(X.z, Y.z, Z.z, pbase + p + 2, qxA, qyA, qzA, kA0, kA1, kA2, rsA);
    tkp(X.z, Y.z, Z.z, pbase + p + 2, qxB, qyB, qzB, kB0, kB1, kB2, rsB);
    tkp(X.w, Y.w, Z.w, pbase + p + 3, qxA, qyA, qzA, kA0, kA1, kA2, rsA);
    tkp(X.w, Y.w, Z.w, pbase + p + 3, qxB, qyB, qzB, kB0, kB1, kB2, rsB);
  }
  size_t PA = ((size_t)(b * NCHUNK + q) * NS + nA) * 4;
  size_t PB = ((size_t)(b * NCHUNK + q) * NS + nB) * 4;
  *(float4*)(pbuf + PA) = make_float4(kA0, kA1, kA2, rsA);
  *(float4*)(pbuf + PB) = make_float4(kB0, kB1, kB2, rsB);
}

// topk stage 2 (unchanged)
__global__ __launch_bounds__(256) void topk_merge_kernel(
    const float* __restrict__ pbuf, float* __restrict__ w3,
    int* __restrict__ idx3) {
  int gid = blockIdx.x * 256 + threadIdx.x;  // = b*NS + n
  int b = gid >> 12;
  int n = gid & (NS - 1);
  float k0 = INFINITY, k1 = INFINITY, k2 = INFINITY;
  float rsum = 0.f;
  #pragma unroll 4
  for (int q = 0; q < NCHUNK; q++) {
    float4 v = *(const float4*)(pbuf + ((size_t)(b * NCHUNK + q) * NS + n) * 4);
    rsum += v.w;
    k2 = __builtin_amdgcn_fmed3f(k1, k2, v.x);
    k1 = __builtin_amdgcn_fmed3f(k0, k1, v.x);
    k0 = fminf(k0, v.x);
    k2 = __builtin_amdgcn_fmed3f(k1, k2, v.y);
    k1 = __builtin_amdgcn_fmed3f(k0, k1, v.y);
    k0 = fminf(k0, v.y);
    k2 = __builtin_amdgcn_fmed3f(k1, k2, v.z);
    k1 = __builtin_amdgcn_fmed3f(k0, k1, v.z);
    k0 = fminf(k0, v.z);
  }
  float inv = 1.0f / rsum;
  uint u0 = __float_as_uint(k0), u1 = __float_as_uint(k1), u2 = __float_as_uint(k2);
  float d0 = __uint_as_float(u0 & 0xFFFFFC00u);
  float d1 = __uint_as_float(u1 & 0xFFFFFC00u);
  float d2 = __uint_as_float(u2 & 0xFFFFFC00u);
  size_t base = (size_t)gid * 3;
  w3[base + 0] = __builtin_amdgcn_rsqf(d0) * inv;
  w3[base + 1] = __builtin_amdgcn_rsqf(d1) * inv;
  w3[base + 2] = __builtin_amdgcn_rsqf(d2) * inv;
  idx3[base + 0] = (int)(u0 & 1023u);
  idx3[base + 1] = (int)(u1 & 1023u);
  idx3[base + 2] = (int)(u2 & 1023u);
}

// ---------------------------------------------------------------------------
// W fp32 -> bf16; blocks 0..15 zero the 8-replica BN stats (4096 f each).
__global__ __launch_bounds__(256) void wcast_kernel(
    const float* __restrict__ W1, const float* __restrict__ W2,
    ushort_t* __restrict__ W1b, ushort_t* __restrict__ W2b,
    float* __restrict__ st1, float* __restrict__ st2) {
  int tid = threadIdx.x;
  if (blockIdx.x < 16) {
    int i = blockIdx.x * 256 + tid;
    st1[i] = 0.f; st2[i] = 0.f;
  }
  int t = blockIdx.x * 256 + tid;
  int n1 = CO * CIN / 4;
  if (t < n1) {
    float4 v = *(const float4*)(W1 + t * 4);
    ushort4 o; o.x = f2bf(v.x); o.y = f2bf(v.y); o.z = f2bf(v.z); o.w = f2bf(v.w);
    *(ushort4*)(W1b + t * 4) = o;
  } else {
    int u = t - n1;
    float4 v = *(const float4*)(W2 + u * 4);
    ushort4 o; o.x = f2bf(v.x); o.y = f2bf(v.y); o.z = f2bf(v.z); o.w = f2bf(v.w);
    *(ushort4*)(W2b + u * 4) = o;
  }
}

// ---------------------------------------------------------------------------
// Transpose points_prev [b][256][1024] f32 -> pptT [b][1024][256] bf16.
__global__ __launch_bounds__(256) void ppT_kernel(
    const float* __restrict__ pp, ushort_t* __restrict__ pptT) {
  __shared__ float tl[64][65];
  int p0 = blockIdx.x * 64, c0 = blockIdx.y * 64, b = blockIdx.z;
  int tid = threadIdx.x;
  const float* P = pp + (size_t)b * CP * NP;
  int pi4 = (tid & 15) * 4, ci = tid >> 4;
  #pragma unroll
  for (int r = 0; r < 4; r++) {
    int cc = ci + 16 * r;
    float4 v = *(const float4*)(P + (size_t)(c0 + cc) * NP + p0 + pi4);
    tl[cc][pi4] = v.x; tl[cc][pi4 + 1] = v.y; tl[cc][pi4 + 2] = v.z; tl[cc][pi4 + 3] = v.w;
  }
  __syncthreads();
  ushort_t* O = pptT + (size_t)b * NP * CP;
  int ci4 = (tid & 15) * 4, pi = tid >> 4;
  #pragma unroll
  for (int r = 0; r < 4; r++) {
    int pr = pi + 16 * r;
    ushort4 o;
    o.x = f2bf(tl[ci4 + 0][pr]); o.y = f2bf(tl[ci4 + 1][pr]);
    o.z = f2bf(tl[ci4 + 2][pr]); o.w = f2bf(tl[ci4 + 3][pr]);
    *(ushort4*)(O + (size_t)(p0 + pr) * CP + c0 + ci4) = o;
  }
}

// Transpose points_skip [b][128][4096] f32 -> x1[b][n][256..383] bf16.
__global__ __launch_bounds__(256) void skipT_kernel(
    const float* __restrict__ sk, ushort_t* __restrict__ x1) {
  __shared__ float tl[64][65];
  int n0 = blockIdx.x * 64, c0 = blockIdx.y * 64, b = blockIdx.z;
  int tid = threadIdx.x;
  const float* S = sk + (size_t)b * CS * NS;
  int ni4 = (tid & 15) * 4, ci = tid >> 4;
  #pragma unroll
  for (int r = 0; r < 4; r++) {
    int cc = ci + 16 * r;
    float4 v = *(const float4*)(S + (size_t)(c0 + cc) * NS + n0 + ni4);
    tl[cc][ni4] = v.x; tl[cc][ni4 + 1] = v.y; tl[cc][ni4 + 2] = v.z; tl[cc][ni4 + 3] = v.w;
  }
  __syncthreads();
  ushort_t* O = x1 + (size_t)b * NS * CIN;
  int ci4 = (tid & 15) * 4, ni = tid >> 4;
  #pragma unroll
  for (int r = 0; r < 4; r++) {
    int nr = ni + 16 * r;
    ushort4 o;
    o.x = f2bf(tl[ci4 + 0][nr]); o.y = f2bf(tl[ci4 + 1][nr]);
    o.z = f2bf(tl[ci4 + 2][nr]); o.w = f2bf(tl[ci4 + 3][nr]);
    *(ushort4*)(O + (size_t)(n0 + nr) * CIN + CP + c0 + ci4) = o;
  }
}

// Interp: x1[b][n][0..255] = sum_k w3[k] * pptT[idx[k]][c].
__global__ __launch_bounds__(256) void interp_kernel(
    const ushort_t* __restrict__ pptT, const float* __restrict__ w3,
    const int* __restrict__ idx3, ushort_t* __restrict__ x1) {
  int tid = threadIdx.x;
  int nl = tid >> 6, l = tid & 63;
  int b = blockIdx.y;
  int n = blockIdx.x * 4 + nl;
  size_t nb = (size_t)b * NS + n;
  int j0 = idx3[nb * 3 + 0], j1 = idx3[nb * 3 + 1], j2 = idx3[nb * 3 + 2];
  float w0 = w3[nb * 3 + 0], w1 = w3[nb * 3 + 1], w2 = w3[nb * 3 + 2];
  const ushort_t* P = pptT + (size_t)b * NP * CP;
  int c = l * 4;
  ushort4 g0 = *(const ushort4*)(P + (size_t)j0 * CP + c);
  ushort4 g1 = *(const ushort4*)(P + (size_t)j1 * CP + c);
  ushort4 g2 = *(const ushort4*)(P + (size_t)j2 * CP + c);
  ushort4 o;
  o.x = f2bf(w0 * bf2f(g0.x) + w1 * bf2f(g1.x) + w2 * bf2f(g2.x));
  o.y = f2bf(w0 * bf2f(g0.y) + w1 * bf2f(g1.y) + w2 * bf2f(g2.y));
  o.z = f2bf(w0 * bf2f(g0.z) + w1 * bf2f(g1.z) + w2 * bf2f(g2.z));
  o.w = f2bf(w0 * bf2f(g0.w) + w1 * bf2f(g1.w) + w2 * bf2f(g2.w));
  *(ushort4*)(x1 + nb * CIN + c) = o;
}

// ---------------------------------------------------------------------------
// MFMA GEMM (round-5 K-loop, the empirical best — untouched). 128x128 tile,
// 4 waves, 4x4 frags of 16x16x32, BK=32, gload_lds + chunk-XOR swizzle.
// ACT: fold relu(a1*x+s1) during reg-staging (gemm2); affine computed in the
// prologue from 8-replica stats. TR_OUT: epilogue writes y transposed
// [b][o][n] (for gemm2 -> linear bnrelu). Stats out: 8-replica atomics.
template <int KD, bool ACT, bool TR_OUT>
__global__ __launch_bounds__(256) void gemm_mfma_kernel(
    const ushort_t* __restrict__ X, const ushort_t* __restrict__ Wb,
    const float* __restrict__ stats_in, const float* __restrict__ g_in,
    const float* __restrict__ bt_in,
    ushort_t* __restrict__ Yb, float* __restrict__ stats) {
  __shared__ __align__(16) char lds_raw[34048];   // ldsX 8K | ldsW 8K; epi 33.8K
  ushort_t* ldsX = (ushort_t*)lds_raw;
  ushort_t* ldsW = (ushort_t*)(lds_raw + 8192);
  __shared__ float ssum[128], ssq[128];
  __shared__ float a1s[ACT ? CO : 1], s1s[ACT ? CO : 1];
  int tid = threadIdx.x;
  int w = tid >> 6, l = tid & 63;
  int bid = blockIdx.x;
  int by = (bid >> 3) & 1;
  int s  = (bid & 7) + 8 * (bid >> 4);
  int bx = s & 31;
  int bz = s >> 5;
  int n0 = bx * 128;
  if (tid < 128) { ssum[tid] = 0.f; ssq[tid] = 0.f; }
  if constexpr (ACT) {
    float sm = 0.f, sq = 0.f;
    #pragma unroll
    for (int r = 0; r < NREP; r++) {
      sm += stats_in[r * 512 + tid];
      sq += stats_in[r * 512 + 256 + tid];
    }
    float cnt = (float)NB * (float)NS;
    float m = sm / cnt;
    float var = fmaxf(sq / cnt - m * m, 0.f);
    float invs = rsqrtf(var + 1e-5f);
    float av = g_in[tid] * invs;
    a1s[tid] = av; s1s[tid] = bt_in[tid] - m * av;
  }
  __syncthreads();

  f32x4 acc[4][4];
  #pragma unroll
  for (int i = 0; i < 4; i++)
    #pragma unroll
    for (int j = 0; j < 4; j++) acc[i][j] = {0.f, 0.f, 0.f, 0.f};

  int wn = (w & 1) * 64, wo = (w >> 1) * 64;
  int lr = l & 15, lk = l >> 4;
  const ushort_t* Xb = X + (size_t)bz * NS * KD;
  int rbase = w * 16 + (l >> 2);
  int cl = l & 3;
  int ksw = 8 * (cl ^ ((rbase >> 1) & 3));   // swizzled k-offset (q-invariant)

  for (int kt = 0; kt < KD / 32; kt++) {
    int k0 = kt * 32;
    int ks = k0 + ksw;
    #pragma unroll
    for (int q = 0; q < 2; q++) {
      int r = q * 64 + rbase;
      gload16(Wb + (size_t)(by * 128 + r) * KD + ks, &ldsW[(q * 64 + w * 16) * 32]);
    }
    if constexpr (!ACT) {
      #pragma unroll
      for (int q = 0; q < 2; q++) {
        int r = q * 64 + rbase;
        gload16(Xb + (size_t)(n0 + r) * KD + ks, &ldsX[(q * 64 + w * 16) * 32]);
      }
    } else {
      float4 av0 = *(const float4*)&a1s[ks];
      float4 av1 = *(const float4*)&a1s[ks + 4];
      float4 sv0 = *(const float4*)&s1s[ks];
      float4 sv1 = *(const float4*)&s1s[ks + 4];
      #pragma unroll
      for (int q = 0; q < 2; q++) {
        int r = q * 64 + rbase;
        const ushort_t* src = Xb + (size_t)(n0 + r) * KD + ks;
        ushort4 v0 = *(const ushort4*)(src);
        ushort4 v1 = *(const ushort4*)(src + 4);
        int4 o;
        o.x = (int)pk2(f2bf(fmaxf(fmaf(av0.x, bf2f(v0.x), sv0.x), 0.f)),
                       f2bf(fmaxf(fmaf(av0.y, bf2f(v0.y), sv0.y), 0.f)));
        o.y = (int)pk2(f2bf(fmaxf(fmaf(av0.z, bf2f(v0.z), sv0.z), 0.f)),
                       f2bf(fmaxf(fmaf(av0.w, bf2f(v0.w), sv0.w), 0.f)));
        o.z = (int)pk2(f2bf(fmaxf(fmaf(av1.x, bf2f(v1.x), sv1.x), 0.f)),
                       f2bf(fmaxf(fmaf(av1.y, bf2f(v1.y), sv1.y), 0.f)));
        o.w = (int)pk2(f2bf(fmaxf(fmaf(av1.z, bf2f(v1.z), sv1.z), 0.f)),
                       f2bf(fmaxf(fmaf(av1.w, bf2f(v1.w), sv1.w), 0.f)));
        *(int4*)&ldsX[(q * 64 + w * 16) * 32 + l * 8] = o;
      }
    }
    __syncthreads();
    short8 a[4], bfr[4];
    #pragma unroll
    for (int i = 0; i < 4; i++) {
      int rr = wn + i * 16 + lr;
      int cs = lk ^ ((rr >> 1) & 3);
      a[i] = *(const short8*)&ldsX[rr * 32 + cs * 8];
    }
    #pragma unroll
    for (int j = 0; j < 4; j++) {
      int rr = wo + j * 16 + lr;
      int cs = lk ^ ((rr >> 1) & 3);
      bfr[j] = *(const short8*)&ldsW[rr * 32 + cs * 8];
    }
    #pragma unroll
    for (int i = 0; i < 4; i++)
      #pragma unroll
      for (int j = 0; j < 4; j++)
        acc[i][j] = __builtin_amdgcn_mfma_f32_16x16x32_bf16(a[i], bfr[j], acc[i][j], 0, 0, 0);
    __syncthreads();
  }

  // ---- epilogue: LDS stat partials + coalesced C write via [128][132] tile
  #pragma unroll
  for (int j = 0; j < 4; j++) {
    int ol = wo + j * 16 + lr;
    float ps = 0.f, pq = 0.f;
    #pragma unroll
    for (int i = 0; i < 4; i++)
      #pragma unroll
      for (int rg = 0; rg < 4; rg++) { float v = acc[i][j][rg]; ps += v; pq += v * v; }
    atomicAdd(&ssum[ol], ps);
    atomicAdd(&ssq[ol], pq);
  }
  ushort_t* lout = (ushort_t*)lds_raw;   // [128][132]
  #pragma unroll
  for (int i = 0; i < 4; i++)
    #pragma unroll
    for (int j = 0; j < 4; j++)
      #pragma unroll
      for (int rg = 0; rg < 4; rg++) {
        int nl = wn + i * 16 + lk * 4 + rg;
        int ol = wo + j * 16 + lr;
        lout[nl * 132 + ol] = f2bf(acc[i][j][rg]);
      }
  __syncthreads();
  if constexpr (!TR_OUT) {
    int row = tid >> 1, half = tid & 1;
    const ushort_t* src = lout + row * 132 + half * 64;
    ushort_t* dst = Yb + ((size_t)bz * NS + n0 + row) * CO + by * 128 + half * 64;
    #pragma unroll
    for (int k = 0; k < 8; k++)
      *(us8*)(dst + k * 8) = *(const us8*)(src + k * 8);
  } else {
    // write y transposed: [b][o][n], 128 o x 128 n tile
    int ol = tid & 127, nh = tid >> 7;
    us8 buf[8];
    #pragma unroll
    for (int k = 0; k < 8; k++) {
      #pragma unroll
      for (int e = 0; e < 8; e++)
        buf[k][e] = lout[(nh * 64 + k * 8 + e) * 132 + ol];
    }
    ushort_t* dst = Yb + ((size_t)bz * CO + by * 128 + ol) * NS + n0 + nh * 64;
    #pragma unroll
    for (int k = 0; k < 8; k++)
      *(us8*)(dst + k * 8) = buf[k];
  }
  if (tid < 128) {
    int rep = bid & (NREP - 1);
    atomicAdd(&stats[rep * 512 + by * 128 + tid], ssum[tid]);
    atomicAdd(&stats[rep * 512 + 256 + by * 128 + tid], ssq[tid]);
  }
}

// ---------------------------------------------------------------------------
// Linear BN2+ReLU: y2T [b][o][n] bf16 -> out [b][o][n] f32. Affine from
// 8-replica stats in prologue. grid 2048 x 256, 4 us8 vectors per thread.
__global__ __launch_bounds__(256) void bnrelu_lin_kernel(
    const ushort_t* __restrict__ y2T, const float* __restrict__ stats_in,
    const float* __restrict__ g_in, const float* __restrict__ bt_in,
    float* __restrict__ out) {
  __shared__ float a2s[CO], s2s[CO];
  int tid = threadIdx.x;
  {
    float sm = 0.f, sq = 0.f;
    #pragma unroll
    for (int r = 0; r < NREP; r++) {
      sm += stats_in[r * 512 + tid];
      sq += stats_in[r * 512 + 256 + tid];
    }
    float cnt = (float)NB * (float)NS;
    float m = sm / cnt;
    float var = fmaxf(sq / cnt - m * m, 0.f);
    float invs = rsqrtf(var + 1e-5f);
    float av = g_in[tid] * invs;
    a2s[tid] = av; s2s[tid] = bt_in[tid] - m * av;
  }
  __syncthreads();
  const size_t NV = (size_t)NB * CO * NS / 8;   // us8 vectors
  for (size_t v = (size_t)blockIdx.x * 256 + tid; v < NV; v += 2048 * 256) {
    size_t flat = v * 8;
    int o = (int)((flat >> 12) & (CO - 1));
    us8 x = *(const us8*)(y2T + flat);
    float av = a2s[o], sv = s2s[o];
    float4 r0, r1;
    r0.x = fmaxf(fmaf(av, bf2f(x[0]), sv), 0.f);
    r0.y = fmaxf(fmaf(av, bf2f(x[1]), sv), 0.f);
    r0.z = fmaxf(fmaf(av, bf2f(x[2]), sv), 0.f);
    r0.w = fmaxf(fmaf(av, bf2f(x[3]), sv), 0.f);
    r1.x = fmaxf(fmaf(av, bf2f(x[4]), sv), 0.f);
    r1.y = fmaxf(fmaf(av, bf2f(x[5]), sv), 0.f);
    r1.z = fmaxf(fmaf(av, bf2f(x[6]), sv), 0.f);
    r1.w = fmaxf(fmaf(av, bf2f(x[7]), sv), 0.f);
    *(float4*)(out + flat) = r0;
    *(float4*)(out + flat + 4) = r1;
  }
}

extern "C" void kernel_launch(void* const* d_in, const int* in_sizes, int n_in,
                              void* d_out, int out_size, void* d_ws, size_t ws_size,
                              hipStream_t stream) {
  const float* xyz_prev    = (const float*)d_in[0];
  const float* xyz_skip    = (const float*)d_in[1];
  const float* points_prev = (const float*)d_in[2];
  const float* points_skip = (const float*)d_in[3];
  const float* W1 = (const float*)d_in[4];
  const float* g1 = (const float*)d_in[5];
  const float* b1 = (const float*)d_in[6];
  const float* W2 = (const float*)d_in[7];
  const float* g2 = (const float*)d_in[8];
  const float* b2 = (const float*)d_in[9];
  float* out = (float*)d_out;

  // workspace layout (256B-aligned sequential allocs)
  char* W = (char*)d_ws;
  size_t off = 0;
  auto alloc = [&](size_t bytes) {
    size_t o = off; off = (off + bytes + 255) & ~(size_t)255; return o;
  };
  ushort_t* x1   = (ushort_t*)(W + alloc((size_t)NB * NS * CIN * 2));  // 50.3MB
  ushort_t* y1b  = (ushort_t*)(W + alloc((size_t)NB * NS * CO * 2));   // 33.6MB
  ushort_t* pptT = (ushort_t*)(W + alloc((size_t)NB * NP * CP * 2));   // 8.4MB
  ushort_t* W1b  = (ushort_t*)(W + alloc((size_t)CO * CIN * 2));
  ushort_t* W2b  = (ushort_t*)(W + alloc((size_t)CO * CO * 2));
  float* w3   = (float*)(W + alloc((size_t)NB * NS * 3 * 4));
  int*   idx3 = (int*)(W + alloc((size_t)NB * NS * 3 * 4));
  float* st1  = (float*)(W + alloc(NREP * 512 * 4));
  float* st2  = (float*)(W + alloc(NREP * 512 * 4));
  size_t y2_off = alloc((size_t)NB * NS * CO * 2);                     // 33.6MB bf16
  bool full = (ws_size >= off);
  // y2T bf16 [b][o][n]: in ws if it fits, else in d_out (33.6MB < 67MB out)
  ushort_t* y2b = full ? (ushort_t*)(W + y2_off) : (ushort_t*)d_out;
  // pbuf (16.8MB, transient, consumed before any y2 write) aliases y2 region
  float* pbuf = full ? (float*)(W + y2_off) : (float*)d_out;

  hipLaunchKernelGGL(topk_chunk_kernel, dim3(NS / 512, NCHUNK, NB), dim3(256), 0,
                     stream, xyz_prev, xyz_skip, pbuf);
  hipLaunchKernelGGL(topk_merge_kernel, dim3(NB * NS / 256), dim3(256), 0, stream,
                     pbuf, w3, idx3);
  hipLaunchKernelGGL(wcast_kernel, dim3((CO * CIN / 4 + CO * CO / 4 + 255) / 256),
                     dim3(256), 0, stream, W1, W2, W1b, W2b, st1, st2);
  hipLaunchKernelGGL(ppT_kernel, dim3(NP / 64, CP / 64, NB), dim3(256), 0, stream,
                     points_prev, pptT);
  hipLaunchKernelGGL(skipT_kernel, dim3(NS / 64, CS / 64, NB), dim3(256), 0, stream,
                     points_skip, x1);
  hipLaunchKernelGGL(interp_kernel, dim3(NS / 4, NB), dim3(256), 0, stream,
                     pptT, w3, idx3, x1);
  hipLaunchKernelGGL((gemm_mfma_kernel<CIN, false, false>), dim3(1024), dim3(256),
                     0, stream, x1, W1b, (const float*)nullptr,
                     (const float*)nullptr, (const float*)nullptr, y1b, st1);
  hipLaunchKernelGGL((gemm_mfma_kernel<CO, true, true>), dim3(1024), dim3(256),
                     0, stream, y1b, W2b, st1, g1, b1, y2b, st2);
  if (full) {
    hipLaunchKernelGGL(bnrelu_lin_kernel, dim3(2048), dim3(256), 0, stream,
                       y2b, st2, g2, b2, out);
  } else {
    // y2b lives in d_out: write final f32 into ws (x1+y1b region, dead), copy
    float* stage = (float*)d_ws;
    hipLaunchKernelGGL(bnrelu_lin_kernel, dim3(2048), dim3(256), 0, stream,
                       y2b, st2, g2, b2, stage);
    hipMemcpyAsync(out, stage, (size_t)NB * NS * CO * 4, hipMemcpyDeviceToDevice,
                   stream);
  }
}